// Round 1
// baseline (1185.099 us; speedup 1.0000x reference)
//
#include <hip/hip_runtime.h>

#define BATCH 1000000
#define C 64
#define D 128
#define NPAIRS 2016   // 64*63/2

// ---------------- stage 1: streaming pass over features ----------------
// Grid-stride by wave: each wave owns whole rows. Lane l handles dims l and l+64.
// LDS accumulator sS[64][128]: ds_add address t*128+l -> bank l%32 -> 2-way (free).
__global__ __launch_bounds__(1024) void stage1_kernel(
        const float* __restrict__ feat, const int* __restrict__ targets,
        float* __restrict__ pSums, float* __restrict__ pCnt,
        double* __restrict__ pSq, int nB) {
    __shared__ float sS[C * D];     // 32 KB
    __shared__ float sC[C];
    __shared__ float sWave[16];

    const int tid = threadIdx.x;
    for (int i = tid; i < C * D; i += 1024) sS[i] = 0.0f;
    if (tid < C) sC[tid] = 0.0f;
    __syncthreads();

    const int lane = tid & 63;
    const int wid  = tid >> 6;                 // 0..15
    const int gwave = blockIdx.x * 16 + wid;
    const int nwaves = nB * 16;

    float lsq = 0.0f;
    for (int r = gwave; r < BATCH; r += nwaves) {
        const int t = targets[r];
        const float* row = feat + (size_t)r * D;
        const float f0 = row[lane];
        const float f1 = row[lane + 64];
        lsq += f0 * f0 + f1 * f1;
        atomicAdd(&sS[t * D + lane], f0);
        atomicAdd(&sS[t * D + 64 + lane], f1);
        if (lane == 0) atomicAdd(&sC[t], 1.0f);
    }

    // wave-level reduce of lsq (width 64)
    for (int off = 32; off > 0; off >>= 1)
        lsq += __shfl_down(lsq, off, 64);
    if (lane == 0) sWave[wid] = lsq;
    __syncthreads();

    if (tid == 0) {
        double s = 0.0;
        for (int w = 0; w < 16; w++) s += (double)sWave[w];
        pSq[blockIdx.x] = s;
    }

    // flush deterministic per-block partials (fully overwrites its region)
    float* dst = pSums + (size_t)blockIdx.x * (C * D);
    for (int i = tid; i < C * D; i += 1024) dst[i] = sS[i];
    if (tid < C) pCnt[blockIdx.x * C + tid] = sC[tid];
}

// ---------------- stage 2: reduce partials -> centers, counts, w_c ----------------
// One block per class, 512 threads: 4-way split over partial-blocks b, dims in lanes.
__global__ __launch_bounds__(512) void stage2_kernel(
        const float* __restrict__ pSums, const float* __restrict__ pCnt,
        float* __restrict__ centers, float* __restrict__ wc, int nB) {
    const int c = blockIdx.x;
    const int tid = threadIdx.x;   // 0..511
    const int d = tid & 127;
    const int g = tid >> 7;        // 0..3

    float s = 0.0f;
    for (int b = g; b < nB; b += 4)
        s += pSums[(size_t)b * (C * D) + c * D + d];

    __shared__ float sred[512];
    sred[tid] = s;
    __syncthreads();
    if (g == 0) s = sred[d] + sred[d + 128] + sred[d + 256] + sred[d + 384];

    // counts reduction
    float cpart = 0.0f;
    for (int b = tid; b < nB; b += 512) cpart += pCnt[b * C + c];
    __syncthreads();
    sred[tid] = cpart;
    __syncthreads();
    for (int off = 256; off > 0; off >>= 1) {
        if (tid < off) sred[tid] += sred[tid + off];
        __syncthreads();
    }
    const float cnt = sred[0];
    const float cc = cnt < 1.0f ? 1.0f : cnt;
    __syncthreads();

    if (g == 0) {
        const float ctr = s / cc;
        centers[c * D + d] = ctr;
        // w_c contribution: 2*sums*center - cnt*center^2  (== cnt*||c||^2 when cnt>=1)
        sred[d] = 2.0f * s * ctr - cnt * ctr * ctr;
    }
    __syncthreads();
    if (tid == 0) {
        float w = 0.0f;
        for (int k = 0; k < D; k++) w += sred[k];
        wc[c] = w;
    }
}

// ---------------- stage 3: pairwise hinge + final combine ----------------
__global__ __launch_bounds__(256) void stage3_kernel(
        const float* __restrict__ centers, const float* __restrict__ wc,
        const double* __restrict__ pSq, float* __restrict__ out, int nB) {
    __shared__ float sCtr[C * 129];   // +1 pad: bank (j+d)%32 -> 2-way (free)
    __shared__ double dred[256];

    const int tid = threadIdx.x;
    for (int idx = tid; idx < C * D; idx += 256) {
        const int i = idx >> 7;
        const int d = idx & 127;
        sCtr[i * 129 + d] = centers[idx];
    }
    __syncthreads();

    // pairwise hinge over upper triangle
    float acc = 0.0f;
    for (int q = tid; q < C * C; q += 256) {
        const int i = q >> 6;
        const int j = q & 63;
        if (j > i) {
            const float* ci = sCtr + i * 129;
            const float* cj = sCtr + j * 129;
            float d2 = 0.0f;
            for (int d = 0; d < D; d++) {
                const float df = ci[d] - cj[d];
                d2 += df * df;
            }
            float h = 2.0f - d2;            // MARGIN = 2.0
            if (h < 0.0f) h = 0.0f;
            const float w = (i == 1 && j == 2) ? 2.0f : 1.0f;
            acc += w * h;
        }
    }

    // sumsq partials
    double dacc = 0.0;
    for (int b = tid; b < nB; b += 256) dacc += pSq[b];

    // per-class w_c
    float wacc = 0.0f;
    if (tid < C) wacc = wc[tid];

    // combined: (sumsq - sum_wc)/B + hinge_sum/NPAIRS
    dred[tid] = (dacc - (double)wacc) * (1.0 / (double)BATCH)
              + (double)acc * (1.0 / (double)NPAIRS);
    __syncthreads();
    for (int off = 128; off > 0; off >>= 1) {
        if (tid < off) dred[tid] += dred[tid + off];
        __syncthreads();
    }
    if (tid == 0) out[0] = (float)dred[0];
}

extern "C" void kernel_launch(void* const* d_in, const int* in_sizes, int n_in,
                              void* d_out, int out_size, void* d_ws, size_t ws_size,
                              hipStream_t stream) {
    const float* feat    = (const float*)d_in[0];
    const int*   targets = (const int*)d_in[1];
    float* out = (float*)d_out;

    // pick nB (stage-1 grid) so partials fit in ws
    int nB = 256;
    while (nB > 1) {
        size_t need = (size_t)nB * (C * D + C) * sizeof(float)   // partial sums + counts
                    + (size_t)nB * sizeof(double)                // partial sumsq
                    + (size_t)(C * D + C) * sizeof(float) + 64;  // centers + wc
        if (need <= ws_size) break;
        nB >>= 1;
    }

    float*  pSums   = (float*)d_ws;                        // [nB][C][D]
    float*  pCnt    = pSums + (size_t)nB * C * D;          // [nB][C]
    double* pSq     = (double*)(pCnt + (size_t)nB * C);    // [nB]  (offset nB*33024 B, 8-aligned)
    float*  centers = (float*)(pSq + nB);                  // [C][D]
    float*  wcv     = centers + C * D;                     // [C]

    stage1_kernel<<<nB, 1024, 0, stream>>>(feat, targets, pSums, pCnt, pSq, nB);
    stage2_kernel<<<C, 512, 0, stream>>>(pSums, pCnt, centers, wcv, nB);
    stage3_kernel<<<1, 256, 0, stream>>>(centers, wcv, pSq, out, nB);
}